// Round 1
// 153.901 us; speedup vs baseline: 1.0203x; 1.0203x over previous
//
#include <hip/hip_runtime.h>
#include <math.h>

#define NN 200
#define ETOT 39800

typedef float float4v __attribute__((ext_vector_type(4)));
typedef short short8 __attribute__((ext_vector_type(8)));
typedef unsigned int uint4v __attribute__((ext_vector_type(4)));

__device__ __forceinline__ float sigf(float x) { return 1.0f / (1.0f + expf(-x)); }

__device__ __forceinline__ unsigned short f2b(float f) {
  unsigned u = __float_as_uint(f);
  u += 0x7fffu + ((u >> 16) & 1u);
  return (unsigned short)(u >> 16);
}
__device__ __forceinline__ float b2f16(unsigned short u) {
  return __uint_as_float(((unsigned)u) << 16);
}
// HW packed f32->bf16 (RNE), guide T12 recipe
__device__ __forceinline__ unsigned pk2(float a, float b) {
  unsigned r;
  asm("v_cvt_pk_bf16_f32 %0, %1, %2" : "=v"(r) : "v"(a), "v"(b));
  return r;
}

// ======================= prep: transposes + conversions + P/Q + composite inputs ===========
// blocks [0,256): w1 [2048][512] -> w1T bf16 [512][2048]
// blocks [256,288): w2 [512][256] -> w2T bf16 [256][512]
// blocks [288,416): wp2 [128][4096] -> Ac rows 0..511: Ac[k*4+o][i]=wp2[k][i*4+o]
// blocks [416,432): Ac rows 512..527: wi/root_w/bp2 columns (12 rows) + 4 zero rows
// blocks [432,500): Bc [272][1024]: rows 0..255 = w3 (bf16), row 256 = b3, rows 257..271 = 0
// blocks [500,516): we2 [256][64] -> we2T bf16 [64][256]
// blocks [516,716): P/Q per node
// blocks [716,916): roi row -> bf16
// block  916: wp1T float4[128]
__global__ __launch_bounds__(256) void k_prep(
    const float* __restrict__ w1, const float* __restrict__ w2, const float* __restrict__ w3,
    const float* __restrict__ b3, const float* __restrict__ wp2, const float* __restrict__ we2,
    const float* __restrict__ bbox, const float* __restrict__ dir,
    const float* __restrict__ we1, const float* __restrict__ be1,
    const float* __restrict__ roi, const float* __restrict__ wp1,
    const float* __restrict__ wi, const float* __restrict__ rootw, const float* __restrict__ bp2,
    unsigned short* __restrict__ w1T, unsigned short* __restrict__ w2T,
    unsigned short* __restrict__ Ac, unsigned short* __restrict__ Bc,
    unsigned short* __restrict__ we2T, unsigned short* __restrict__ roiB,
    float* __restrict__ P, float* __restrict__ Q, float* __restrict__ wp1T) {
  __shared__ float lds[64][65];
  const int b = blockIdx.x, tid = threadIdx.x;

  if (b < 288) {
    // LDS-tiled transpose f32[K][N] -> bf16[N][K]
    const float* Wf;
    unsigned short* Wt;
    int K, N, t;
    if (b < 256) { Wf = w1; Wt = w1T; K = 2048; N = 512; t = b; }
    else { Wf = w2; Wt = w2T; K = 512; N = 256; t = b - 256; }
    const int K64 = K >> 6;
    const int kt = t % K64, nt = t / K64;
#pragma unroll 4
    for (int i = 0; i < 16; ++i) {
      int idx = tid + i * 256;
      int r = idx >> 6, c = idx & 63;
      lds[r][c] = Wf[(size_t)(kt * 64 + r) * N + nt * 64 + c];
    }
    __syncthreads();
#pragma unroll 4
    for (int i = 0; i < 16; ++i) {
      int idx = tid + i * 256;
      int r = idx >> 6, c = idx & 63;
      Wt[(size_t)(nt * 64 + r) * K + kt * 64 + c] = f2b(lds[c][r]);
    }
  } else if (b < 416) {
    int k = b - 288;                         // 0..127
    int o = tid >> 6, l = tid & 63;
    const float* src = wp2 + (size_t)k * 4096;
    unsigned short* dst = Ac + (size_t)(k * 4 + o) * 1024;
    for (int i = l; i < 1024; i += 64) dst[i] = f2b(src[i * 4 + o]);
  } else if (b < 432) {
    int r = b - 416;                         // 0..15 -> Ac row 512+r
    unsigned short* dst = Ac + (size_t)(512 + r) * 1024;
    const float* src = (r < 4) ? (wi + r) : (r < 8) ? (rootw + (r - 4))
                     : (r < 12) ? (bp2 + (r - 8)) : nullptr;
    for (int i = tid; i < 1024; i += 256)
      dst[i] = src ? f2b(src[i * 4]) : (unsigned short)0;
  } else if (b < 500) {
    int rb = (b - 432) * 4;                  // 4 rows of Bc per block
#pragma unroll
    for (int j = 0; j < 16; ++j) {
      int idx = tid + j * 256;
      int row = rb + (idx >> 10), i = idx & 1023;
      float val = (row < 256) ? w3[(size_t)row * 1024 + i] : (row == 256 ? b3[i] : 0.0f);
      Bc[(size_t)row * 1024 + i] = f2b(val);
    }
  } else if (b < 516) {
    int f = (b - 500) * 256 + tid;           // 0..4095
    int c = f >> 6, k0 = (f & 63) * 4;
#pragma unroll
    for (int q = 0; q < 4; ++q)
      we2T[c * 256 + k0 + q] = f2b(we2[(k0 + q) * 64 + c]);
  } else if (b < 716) {
    int n = b - 516, c = tid;
    float a[8];
#pragma unroll
    for (int r = 0; r < 4; ++r) a[r] = bbox[n * 4 + r] * (1.0f / 1024.0f);
#pragma unroll
    for (int r = 0; r < 4; ++r) a[4 + r] = dir[n * 4 + r];
    float p = be1[c], q = 0.0f;
#pragma unroll
    for (int r = 0; r < 8; ++r) {
      p += a[r] * we1[r * 256 + c];
      q += a[r] * we1[(8 + r) * 256 + c];
    }
    P[n * 256 + c] = p;
    Q[n * 256 + c] = q;
  } else if (b < 916) {
    int n = b - 716;
    const float4v* R4 = (const float4v*)(roi + (size_t)n * 2048);
    unsigned long long* O = (unsigned long long*)(roiB + (size_t)n * 2048);
#pragma unroll
    for (int j = 0; j < 2; ++j) {
      int idx = tid + j * 256;
      float4v v = R4[idx];
      union { unsigned u[2]; unsigned long long ll; } pk;
      pk.u[0] = pk2(v[0], v[1]);
      pk.u[1] = pk2(v[2], v[3]);
      O[idx] = pk.ll;
    }
  } else {
    if (tid < 128) {
      float4v v = {wp1[tid], wp1[128 + tid], wp1[256 + tid], wp1[384 + tid]};
      ((float4v*)wp1T)[tid] = v;
    }
  }
}

// ======================= MFMA GEMM core: 16x16 out tile, 4 waves split K, dual acc ==========
__device__ __forceinline__ float4v mfma16(short8 a, short8 b, float4v c) {
  return __builtin_amdgcn_mfma_f32_16x16x32_bf16(a, b, c, 0, 0, 0);
}

template <int KSTEPS>
__device__ __forceinline__ float tile_core(const unsigned short* __restrict__ A,
                                           const unsigned short* __restrict__ B,
                                           int m0, int n0, int K,
                                           float (&red)[4][16][17]) {
  const int tid = threadIdx.x, lane = tid & 63, wv = tid >> 6;
  const int mr = lane & 15, quad = lane >> 4;
  const unsigned short* Ap = A + (size_t)(m0 + mr) * K + wv * (KSTEPS * 32) + quad * 8;
  const unsigned short* Bp = B + (size_t)(n0 + mr) * K + wv * (KSTEPS * 32) + quad * 8;
  float4v acc0 = {0.f, 0.f, 0.f, 0.f}, acc1 = {0.f, 0.f, 0.f, 0.f};
#pragma unroll
  for (int s = 0; s < KSTEPS; s += 2) {
    acc0 = mfma16(*(const short8*)(Ap + s * 32), *(const short8*)(Bp + s * 32), acc0);
    acc1 = mfma16(*(const short8*)(Ap + (s + 1) * 32), *(const short8*)(Bp + (s + 1) * 32), acc1);
  }
  float4v acc = acc0 + acc1;
#pragma unroll
  for (int r = 0; r < 4; ++r) red[wv][quad * 4 + r][mr] = acc[r];
  __syncthreads();
  const int row = tid >> 4, col = tid & 15;
  return red[0][row][col] + red[1][row][col] + red[2][row][col] + red[3][row][col];
}

// ======================= gemm1 (roiB@w1T) + compose (Ac@Bc) in ONE launch ===================
// blocks [0,416): h1 = relu(roiB @ w1T + b1), grid 13x32
// blocks [416,977): CT[c][j] = bf16( sum_i Ac[c][i]*Bc[j][i] ), j<256; biasT[c] = col 256.
__global__ __launch_bounds__(256) void k_gemm1_compose(
    const unsigned short* __restrict__ roiB, const unsigned short* __restrict__ w1T,
    const float* __restrict__ b1, unsigned short* __restrict__ h1,
    const unsigned short* __restrict__ Ac, const unsigned short* __restrict__ Bc,
    unsigned short* __restrict__ CT, float* __restrict__ biasT) {
  __shared__ float red[4][16][17];
  const int bid = blockIdx.x, tid = threadIdx.x;
  if (bid < 416) {
    const int m0 = (bid % 13) * 16, n0 = (bid / 13) * 16;
    float v = tile_core<16>(roiB, w1T, m0, n0, 2048, red);
    const int row = tid >> 4, col = tid & 15;
    v += b1[n0 + col];
    v = fmaxf(v, 0.f);
    h1[(size_t)(m0 + row) * 512 + n0 + col] = f2b(v);
  } else {
    const int t = bid - 416;
    const int m0 = (t % 33) * 16, n0 = (t / 33) * 16;
    float v = tile_core<8>(Ac, Bc, m0, n0, 1024, red);
    const int row = tid >> 4, col = tid & 15;
    const int c = n0 + col;
    if (c < 256) CT[(size_t)(m0 + row) * 256 + c] = f2b(v);
    else if (c == 256) biasT[m0 + row] = v;
  }
}

// ======================= gemm2: h2 = relu(h1 @ w2T + b2) ====================================
__global__ __launch_bounds__(256) void k_gemm2(const unsigned short* __restrict__ h1,
                                               const unsigned short* __restrict__ w2T,
                                               const float* __restrict__ b2,
                                               unsigned short* __restrict__ h2) {
  __shared__ float red[4][16][17];
  const int m0 = blockIdx.x * 16, n0 = blockIdx.y * 16, tid = threadIdx.x;
  float v = tile_core<4>(h1, w2T, m0, n0, 512, red);
  const int row = tid >> 4, col = tid & 15;
  v += b2[n0 + col];
  v = fmaxf(v, 0.f);
  h2[(size_t)(m0 + row) * 256 + n0 + col] = f2b(v);
}

// ======================= Tfused: everything downstream of x in one GEMM =====================
// out[n][c] = h2[n]·CT[c] + biasT[c]; c<512 -> Tm; c in 512..523 -> nce/out0-init/U.
__global__ __launch_bounds__(256) void k_tfused(const unsigned short* __restrict__ h2,
                                                const unsigned short* __restrict__ CT,
                                                const float* __restrict__ biasT,
                                                const float* __restrict__ bi,
                                                const float* __restrict__ rootb,
                                                float* __restrict__ Tm, float* __restrict__ out1,
                                                float* __restrict__ out0, float* __restrict__ U) {
  __shared__ float red[4][16][17];
  const int m0 = blockIdx.x * 16, n0 = blockIdx.y * 16, tid = threadIdx.x;
  float v = tile_core<2>(h2, CT, m0, n0, 256, red);
  const int row = tid >> 4, col = tid & 15;
  const int n = m0 + row, c = n0 + col;
  v += biasT[c];
  if (c < 512) {
    Tm[(size_t)n * 512 + c] = v;
  } else if (n < NN) {
    int r = c - 512;
    if (r < 4) out1[n * 4 + r] = sigf(v + bi[r]);
    else if (r < 8) out0[n * 4 + (r - 4)] = v + rootb[r - 4];
    else if (r < 12) U[n * 4 + (r - 8)] = v;
  }
}

// ======================= fused edge kernel (MFMA + LDS-staged tail) =======================
__global__ __launch_bounds__(256) void k_edge(
    const float* __restrict__ P, const float* __restrict__ Q,
    const unsigned short* __restrict__ we2T,
    const float* __restrict__ be2, const float* __restrict__ we3, const float* __restrict__ be3,
    const float* __restrict__ wp1T, const float* __restrict__ bp1,
    const float* __restrict__ pri,
    const float* __restrict__ T, const float* __restrict__ U,
    float* __restrict__ out0, float* __restrict__ out_ea) {
  __shared__ int src_s[64], dst_s[64];
  __shared__ float ea_s[64][4];
  __shared__ float4v wp1s[128];
  __shared__ float bp1s[128];
  __shared__ float4v Ts[2][128];
  __shared__ float Us[2][4];

  const int tid = threadIdx.x;
  const int e0 = blockIdx.x * 64;
  const int s_lo = e0 / 199;

  if (tid < 64) {
    int e = e0 + tid;
    int i = -1, j = 0;
    if (e < ETOT) {
      i = e / 199;
      int jj = e - i * 199;
      j = jj + (jj >= i ? 1 : 0);
    }
    src_s[tid] = i;
    dst_s[tid] = j;
  }
  if (tid < 128) {
    wp1s[tid] = ((const float4v*)wp1T)[tid];
    bp1s[tid] = bp1[tid];
  }
  {
    int row = tid >> 7, c = tid & 127;
    Ts[row][c] = ((const float4v*)T)[(s_lo + row) * 128 + c];  // row s_lo+1 may read pad (T has 208 rows)
  }
  if (tid < 8) {
    int s = min(s_lo + (tid >> 2), 199);
    Us[tid >> 2][tid & 3] = U[s * 4 + (tid & 3)];
  }
  __syncthreads();

  const int lane = tid & 63;
  const int wv = tid >> 6;
  const int m = lane & 15;
  const int quad = lane >> 4;
  const int eloc = wv * 16 + m;
  const int si = src_s[eloc];
  const int dj = dst_s[eloc];

  float4v acc[4];
#pragma unroll
  for (int ct = 0; ct < 4; ++ct) { acc[ct][0] = 0.f; acc[ct][1] = 0.f; acc[ct][2] = 0.f; acc[ct][3] = 0.f; }

  const short8* W8 = (const short8*)we2T;

  for (int ks = 0; ks < 8; ++ks) {
    union { short8 s; uint4v u; } af;
    af.s = (short8)0;
    if (si >= 0) {
      const float4v* p4 = (const float4v*)(P + si * 256 + ks * 32 + quad * 8);
      const float4v* q4 = (const float4v*)(Q + dj * 256 + ks * 32 + quad * 8);
      float4v v0 = p4[0] + q4[0];
      float4v v1 = p4[1] + q4[1];
      af.u[0] = pk2(fmaxf(v0[0], 0.f), fmaxf(v0[1], 0.f));
      af.u[1] = pk2(fmaxf(v0[2], 0.f), fmaxf(v0[3], 0.f));
      af.u[2] = pk2(fmaxf(v1[0], 0.f), fmaxf(v1[1], 0.f));
      af.u[3] = pk2(fmaxf(v1[2], 0.f), fmaxf(v1[3], 0.f));
    }
#pragma unroll
    for (int ct = 0; ct < 4; ++ct) {
      short8 bf = W8[(ct * 16 + m) * 32 + ks * 4 + quad];
      acc[ct] = __builtin_amdgcn_mfma_f32_16x16x32_bf16(af.s, bf, acc[ct], 0, 0, 0);
    }
  }

  // eh2 = relu(acc + be2); ev = eh2 @ we3 (shfl-reduce over 64 cols)
  float ev[4][3];
#pragma unroll
  for (int r = 0; r < 4; ++r) { ev[r][0] = 0.f; ev[r][1] = 0.f; ev[r][2] = 0.f; }
#pragma unroll
  for (int ct = 0; ct < 4; ++ct) {
    const int col = ct * 16 + m;
    const float b2v = be2[col];
    const float w0 = we3[col * 3 + 0], w1v = we3[col * 3 + 1], w2v = we3[col * 3 + 2];
#pragma unroll
    for (int r = 0; r < 4; ++r) {
      float e2 = fmaxf(acc[ct][r] + b2v, 0.f);
      ev[r][0] += e2 * w0;
      ev[r][1] += e2 * w1v;
      ev[r][2] += e2 * w2v;
    }
  }
#pragma unroll
  for (int r = 0; r < 4; ++r)
#pragma unroll
    for (int p = 0; p < 3; ++p) {
      float v = ev[r][p];
      v += __shfl_xor(v, 1, 64);
      v += __shfl_xor(v, 2, 64);
      v += __shfl_xor(v, 4, 64);
      v += __shfl_xor(v, 8, 64);
      ev[r][p] = v;
    }
  if (m == 0) {
#pragma unroll
    for (int r = 0; r < 4; ++r) {
      int el = wv * 16 + quad * 4 + r;
      int ss = src_s[el], dd = dst_s[el];
      if (ss >= 0) {
        float4v o;
        o[0] = sigf(ev[r][0] + be3[0]);
        o[1] = sigf(ev[r][1] + be3[1]);
        o[2] = sigf(ev[r][2] + be3[2]);
        o[3] = (pri[ss] > pri[dd]) ? 1.0f : 0.0f;
        *(float4v*)&ea_s[el][0] = o;
        *(float4v*)(out_ea + (size_t)(e0 + el) * 4) = o;
      }
    }
  }
  __syncthreads();

  // tail: h = relu(bp1 + ea@wp1) [128]; msg = h @ T[src]; 4 threads/edge, all LDS
  const int ee = tid >> 2, pp = tid & 3;
  const int s2 = src_s[ee], d2 = dst_s[ee];
  float4v pm = {0.f, 0.f, 0.f, 0.f};
  if (s2 >= 0) {
    const int srow = s2 - s_lo;
    const float c0 = ea_s[ee][0], c1 = ea_s[ee][1], c2 = ea_s[ee][2], c3 = ea_s[ee][3];
#pragma unroll 8
    for (int t = pp; t < 128; t += 4) {
      float4v w4 = wp1s[t];
      float hv = bp1s[t] + c0 * w4[0] + c1 * w4[1] + c2 * w4[2] + c3 * w4[3];
      hv = fmaxf(hv, 0.f);
      pm += hv * Ts[srow][t];
    }
  }
#pragma unroll
  for (int o = 0; o < 4; ++o) {
    float v = pm[o];
    v += __shfl_xor(v, 1, 64);
    v += __shfl_xor(v, 2, 64);
    pm[o] = v;
  }
  if (s2 >= 0) atomicAdd(&out0[d2 * 4 + pp], Us[s2 - s_lo][pp] + pm[pp]);
}

extern "C" void kernel_launch(void* const* d_in, const int* in_sizes, int n_in,
                              void* d_out, int out_size, void* d_ws, size_t ws_size,
                              hipStream_t stream) {
  (void)in_sizes; (void)n_in; (void)out_size; (void)ws_size;
  const float* roi   = (const float*)d_in[0];
  const float* bbox  = (const float*)d_in[1];
  const float* dir   = (const float*)d_in[2];
  const float* pri   = (const float*)d_in[3];
  const float* w1    = (const float*)d_in[4];
  const float* b1    = (const float*)d_in[5];
  const float* w2    = (const float*)d_in[6];
  const float* b2    = (const float*)d_in[7];
  const float* w3    = (const float*)d_in[8];
  const float* b3    = (const float*)d_in[9];
  const float* wi    = (const float*)d_in[10];
  const float* bi    = (const float*)d_in[11];
  const float* we1   = (const float*)d_in[12];
  const float* be1   = (const float*)d_in[13];
  const float* we2   = (const float*)d_in[14];
  const float* be2   = (const float*)d_in[15];
  const float* we3   = (const float*)d_in[16];
  const float* be3   = (const float*)d_in[17];
  const float* wp1   = (const float*)d_in[18];
  const float* bp1   = (const float*)d_in[19];
  const float* wp2   = (const float*)d_in[20];
  const float* bp2   = (const float*)d_in[21];
  const float* rootw = (const float*)d_in[22];
  const float* rootb = (const float*)d_in[23];

  float* out0 = (float*)d_out;        // next_actions [200,4]  (agg accumulated here)
  float* out1 = out0 + 800;           // node_concepts_explicit[0] [200,4]
  float* out2 = out0 + 1600;          // edge_attributes[0] [39800,4]

  // ---- workspace layout (ushort units) ----
  unsigned short* us = (unsigned short*)d_ws;
  unsigned short* w1T  = us;                 // [512][2048]
  unsigned short* w2T  = us + 1048576;       // [256][512]
  unsigned short* Ac   = us + 1179648;       // [528][1024]  rows 0..511 WrT, 512..527 wcol/zero
  unsigned short* Bc   = us + 1720320;       // [272][1024]  w3 / b3 / zero
  unsigned short* we2T = us + 1998848;       // [64][256]
  unsigned short* roiB = us + 2015232;       // [208][2048]
  unsigned short* h1   = us + 2441216;       // [208][512]
  unsigned short* h2   = us + 2547712;       // [208][256]
  unsigned short* CT   = us + 2600960;       // [528][256]   composite (bf16)
  float* fb    = (float*)(us + 2736128);
  float* Tm    = fb;                         // [208][512]
  float* Pm    = fb + 106496;                // [200][256]
  float* Qm    = fb + 157696;                // [200][256]
  float* Um    = fb + 208896;                // [200][4]
  float* wp1Tp = fb + 209696;                // float4[128]
  float* biasT = fb + 210208;                // [528]

  // 1) prep: all transposes/conversions + P/Q + composite operands (917 blocks)
  k_prep<<<917, 256, 0, stream>>>(w1, w2, w3, b3, wp2, we2, bbox, dir, we1, be1, roi, wp1,
                                  wi, rootw, bp2,
                                  w1T, w2T, Ac, Bc, we2T, roiB, Pm, Qm, wp1Tp);

  // 2) gemm1 (node MLP layer 1) + w3-composition GEMM, one launch (977 blocks)
  k_gemm1_compose<<<977, 256, 0, stream>>>(roiB, w1T, b1, h1, Ac, Bc, CT, biasT);

  // 3) node MLP layer 2
  k_gemm2<<<dim3(13, 16), 256, 0, stream>>>(h1, w2T, b2, h2);

  // 4) fused tail GEMM: T + nce(out1) + out0-init + U from h2 directly
  k_tfused<<<dim3(13, 33), 256, 0, stream>>>(h2, CT, biasT, bi, rootb, Tm, out1, out0, Um);

  // 5) fused edge pipeline (atomics straight into out0)
  k_edge<<<622, 256, 0, stream>>>(Pm, Qm, we2T, be2, we3, be3, wp1Tp, bp1, pri, Tm, Um, out0, out2);
}